// Round 14
// baseline (159.879 us; speedup 1.0000x reference)
//
#include <hip/hip_runtime.h>

// CTC loss forward (sum), faithful to the JAX reference.
// T=2048, N=256, C=128, L=200, S=2L+1=401.
//
// Round-13 structure (proven, 151us): one workgroup (4 waves) per sample,
// wave w owns states 128w..128w+127, 2/lane (s0=2idx blank, s1=2idx+1 label).
// Intra-wave halo via DPP wave_shr:1 (old operand injects the cross-wave
// boundary). Cross-wave left->right only, 16-step blocks, monotonic per-wave
// flags, double-buffered boundary prefetch, batched lane-63 boundary bursts.
// Wave 0 never waits. Emission loads via opaque-VGPR offsets (stay VMEM).
//
// Round-14 delta: SOFTWARE EXTENDED-RANGE FLOATS. State = (m fp32, E int32),
// value = m*2^E, exact and unlimited-range (fixes r8/r9's per-wave-scale
// failure WITHOUT anchors/seams). Per step:
//   Emax = max3(E1,E0,Eh); t_i = ldexp(m_i, E_i-Emax)  (full-rate v_ldexp)
//   s1 = t1 + t0 + th*msk;  s0 = t0 + th
//   m1' = s1*exp2(K*scL); m0' = s0*exp2(K*scB); E' = Emax
// The only transcendentals are the two emission exp2s, whose operands were
// prefetched 16 steps ago -> OFF the dependency chain. The serial chain is
// DPP->max3->sub->ldexp->add->mul (~28cy), no trans (was exp2+log ~50cy+
// 5 dependent trans stalls ~100cy). Renorm (m,E) every 4 steps via exponent
// bit-extract + ldexp (worst drift 4*(-36) bits stays normal fp32).
// Dead states exact (0, -2^28). Boundary = (m,E) pairs in twin LDS arrays.

#define TT 2048
#define NN 256
#define CC 128
#define LL 200

#define K_LOG2E 1.4426950408889634f
#define K_LN2   0.6931471805599453f
#define EDEAD   (-(1 << 28))
#define NC4     131072u      /* NN*CC*4 bytes: stride between time rows */

__global__ __launch_bounds__(256, 1)
void ctc_alpha(const float* __restrict__ pred,
               const int* __restrict__ target,
               const int* __restrict__ tlen,
               float* __restrict__ loss_ws)
{
    // [w][b][k]: boundary state 128w+127 AFTER step 16b+1+k, as (m,E) pair.
    // Row 4 = dead (wave 0's virtual producer).
    __shared__ float blkM[5][128][16];
    __shared__ int   blkE[5][128][16];
    __shared__ int   flags[8];     // [w]=blocks completed; [7]=INT_MAX dummy

    const int tid  = threadIdx.x;
    const int wid  = tid >> 6;
    const int lane = tid & 63;
    const int n    = blockIdx.x;

    if (tid < 8) flags[tid] = (tid >= 4) ? 0x7fffffff : 0;
    for (int i = tid; i < 128 * 16; i += 256) {
        ((float*)blkM[4])[i] = 0.0f;
        ((int*)blkE[4])[i]   = EDEAD;
    }

    // per-state constants. Reference quirk: starts[0]=0, starts[n>0]=tlen[n-1].
    const int start = (n == 0) ? 0 : tlen[n - 1];
    const int idx   = (wid << 6) | lane;     // s0 = 2*idx (blank), s1 = 2*idx+1 (label)
    int lab1 = 0; float msk1 = 0.0f;
    if (idx < LL) {
        lab1 = target[start + idx];
        if (idx >= 1 && lab1 != target[start + idx - 1]) msk1 = 1.0f;  // skip allowed
    }

    // ---- alpha_0: only states 0,1 (idx==0) live; (m,E) exact split ----
    float m0, m1; int E0, E1;
    {
        const float xB = K_LOG2E * pred[n * CC];
        const float xL = K_LOG2E * pred[n * CC + lab1];
        const float fB = floorf(xB), fL = floorf(xL);
        m0 = (idx == 0) ? __builtin_amdgcn_exp2f(xB - fB) : 0.0f;
        m1 = (idx == 0) ? __builtin_amdgcn_exp2f(xL - fL) : 0.0f;
        E0 = (idx == 0) ? (int)fB : EDEAD;
        E1 = (idx == 0) ? (int)fL : EDEAD;
    }
    __syncthreads();   // flags + dead row visible before any spin

    // ---- emission pipeline, depth 16 (rows t..t+15 resident) ----
    const char* pcRow = (const char*)pred + (size_t)(NN * CC + n * CC) * 4u;  // row 1
    uint32_t vB = 0u;
    uint32_t vL = (uint32_t)lab1 * 4u;
    asm volatile("" : "+v"(vB), "+v"(vL));    // opaque: forbid s_load scalarization
    float scB[16], scL[16];
#pragma unroll
    for (int ph = 0; ph < 16; ++ph) {                          // rows 1..16
        scB[ph] = *(const float*)(pcRow + vB);
        scL[ph] = *(const float*)(pcRow + vL);
        pcRow += NC4;
    }

    float (* const blkCM)[16] = blkM[(wid == 0) ? 4 : (wid - 1)];
    int   (* const blkCE)[16] = blkE[(wid == 0) ? 4 : (wid - 1)];
    float (* const blkWM)[16] = blkM[wid];
    int   (* const blkWE)[16] = blkE[wid];
    volatile int* pflag = &flags[(wid == 0) ? 7 : (wid - 1)];
    volatile int* mflag = &flags[wid];
    int fval = *pflag;

    float bndAM[16], bndBM[16], bwM[16];
    int   bndAE[16], bndBE[16], bwE[16];
    float bprevM = 0.0f;        // boundary after step 0: dead for every wave
    int   bprevE = EDEAD;

#define LOAD_BLK(DM, DE, B)                                                    \
    {                                                                          \
        const float4* qm = (const float4*)&blkCM[B][0];                        \
        const int4*   qe = (const int4*)&blkCE[B][0];                          \
        const float4 a0 = qm[0], a1 = qm[1], a2 = qm[2], a3 = qm[3];           \
        const int4   b0 = qe[0], b1 = qe[1], b2 = qe[2], b3 = qe[3];           \
        DM[0]=a0.x;  DM[1]=a0.y;  DM[2]=a0.z;  DM[3]=a0.w;                     \
        DM[4]=a1.x;  DM[5]=a1.y;  DM[6]=a1.z;  DM[7]=a1.w;                     \
        DM[8]=a2.x;  DM[9]=a2.y;  DM[10]=a2.z; DM[11]=a2.w;                    \
        DM[12]=a3.x; DM[13]=a3.y; DM[14]=a3.z; DM[15]=a3.w;                    \
        DE[0]=b0.x;  DE[1]=b0.y;  DE[2]=b0.z;  DE[3]=b0.w;                     \
        DE[4]=b1.x;  DE[5]=b1.y;  DE[6]=b1.z;  DE[7]=b1.w;                     \
        DE[8]=b2.x;  DE[9]=b2.y;  DE[10]=b2.z; DE[11]=b2.w;                    \
        DE[12]=b3.x; DE[13]=b3.y; DE[14]=b3.z; DE[15]=b3.w;                    \
    }

#define STORE_BLK(B)                                                           \
    if (lane == 63) {                                                          \
        float4* dm = (float4*)&blkWM[B][0];                                    \
        int4*   de = (int4*)&blkWE[B][0];                                      \
        dm[0] = make_float4(bwM[0],  bwM[1],  bwM[2],  bwM[3]);                \
        dm[1] = make_float4(bwM[4],  bwM[5],  bwM[6],  bwM[7]);                \
        dm[2] = make_float4(bwM[8],  bwM[9],  bwM[10], bwM[11]);               \
        dm[3] = make_float4(bwM[12], bwM[13], bwM[14], bwM[15]);               \
        de[0] = make_int4(bwE[0],  bwE[1],  bwE[2],  bwE[3]);                  \
        de[1] = make_int4(bwE[4],  bwE[5],  bwE[6],  bwE[7]);                  \
        de[2] = make_int4(bwE[8],  bwE[9],  bwE[10], bwE[11]);                 \
        de[3] = make_int4(bwE[12], bwE[13], bwE[14], bwE[15]);                 \
    }

    // One step, PH = 0..15. Halo (mh,Eh) = prev lane's (m1,E1) via 2 DPPs;
    // lane0 <- boundary pair via the DPP old operands. No trans on the chain.
#define CTC_STEP(PH, BVM, BVE, PREF)                                           \
    {                                                                          \
        const float holdM = ((PH) == 0) ? bprevM : BVM[((PH) + 15) & 15];      \
        const int   holdE = ((PH) == 0) ? bprevE : BVE[((PH) + 15) & 15];      \
        const int mhi = __builtin_amdgcn_update_dpp(                           \
            __float_as_int(holdM), __float_as_int(m1), 0x138, 0xf, 0xf, false);\
        const int Eh  = __builtin_amdgcn_update_dpp(                           \
            holdE, E1, 0x138, 0xf, 0xf, false);                                \
        const float mh = __int_as_float(mhi);                                  \
        const int Emax = max(max(E1, E0), Eh);                                 \
        const float t1 = ldexpf(m1, E1 - Emax);                                \
        const float t0 = ldexpf(m0, E0 - Emax);                                \
        const float th = ldexpf(mh, Eh - Emax);                                \
        const float eL = __builtin_amdgcn_exp2f(K_LOG2E * scL[PH]);            \
        const float eB = __builtin_amdgcn_exp2f(K_LOG2E * scB[PH]);            \
        const float s1 = (t1 + t0) + th * msk1;                                \
        const float s0 = t0 + th;                                              \
        m1 = s1 * eL;  E1 = Emax;                                              \
        m0 = s0 * eB;  E0 = Emax;                                              \
        bwM[PH] = m1;  bwE[PH] = E1;                                           \
        if (((PH) & 3) == 3) {   /* renorm every 4 steps (all full-rate) */    \
            const int e1 = (int)((__float_as_uint(m1) >> 23) & 255u) - 126;    \
            m1 = ldexpf(m1, -e1);  E1 += e1;                                   \
            const int e0 = (int)((__float_as_uint(m0) >> 23) & 255u) - 126;    \
            m0 = ldexpf(m0, -e0);  E0 += e0;                                   \
        }                                                                      \
        if (PREF) {                                                            \
            scB[PH] = *(const float*)(pcRow + vB);                             \
            scL[PH] = *(const float*)(pcRow + vL);                             \
            pcRow += NC4;                                                      \
        }                                                                      \
    }

#define RUN_BLOCK(B, UM, UE, PM, PE, NEED, LASTPREF)                           \
    {                                                                          \
        const int need_ = (NEED);                                              \
        if (fval < need_) { do { fval = *pflag; } while (fval < need_); }      \
        asm volatile("" ::: "memory");                                         \
        LOAD_BLK(PM, PE, (B) + 1)                                              \
        CTC_STEP( 0, UM, UE, 1) CTC_STEP( 1, UM, UE, 1) CTC_STEP( 2, UM, UE, 1)\
        CTC_STEP( 3, UM, UE, 1) CTC_STEP( 4, UM, UE, 1) CTC_STEP( 5, UM, UE, 1)\
        CTC_STEP( 6, UM, UE, 1) CTC_STEP( 7, UM, UE, 1) CTC_STEP( 8, UM, UE, 1)\
        CTC_STEP( 9, UM, UE, 1) CTC_STEP(10, UM, UE, 1) CTC_STEP(11, UM, UE, 1)\
        CTC_STEP(12, UM, UE, 1) CTC_STEP(13, UM, UE, 1) CTC_STEP(14, UM, UE, 1)\
        CTC_STEP(15, UM, UE, LASTPREF)                                         \
        STORE_BLK(B)                                                           \
        asm volatile("" ::: "memory");       /* burst before flag post */      \
        if (lane == 0) *mflag = (B) + 1;                                       \
        bprevM = UM[15];  bprevE = UE[15];                                     \
        fval = *pflag;                                                         \
    }

    // prologue: block 0's boundaries (written by producer's block 0)
    if (fval < 1) { do { fval = *pflag; } while (fval < 1); }
    asm volatile("" ::: "memory");
    LOAD_BLK(bndAM, bndAE, 0)

    // main: blocks 0..125 (t = 1..2016), ping-pong A/B, prefetch b+1
    for (int bb = 0; bb < 63; ++bb) {
        RUN_BLOCK(2 * bb,     bndAM, bndAE, bndBM, bndBE, 2 * bb + 2, 1)
        RUN_BLOCK(2 * bb + 1, bndBM, bndBE, bndAM, bndAE, 2 * bb + 3, 1)
    }

    // block 126 (t=2017..2032): prefetch block 127 (needs producer DONE=128)
    RUN_BLOCK(126, bndAM, bndAE, bndBM, bndBE, 128, 0)

    // tail block 127: t = 2033..2047 (15 steps), data already in bndB*.
    {
        asm volatile("" ::: "memory");
        CTC_STEP( 0, bndBM, bndBE, 0) CTC_STEP( 1, bndBM, bndBE, 0)
        CTC_STEP( 2, bndBM, bndBE, 0) CTC_STEP( 3, bndBM, bndBE, 0)
        CTC_STEP( 4, bndBM, bndBE, 0) CTC_STEP( 5, bndBM, bndBE, 0)
        CTC_STEP( 6, bndBM, bndBE, 0) CTC_STEP( 7, bndBM, bndBE, 0)
        CTC_STEP( 8, bndBM, bndBE, 0) CTC_STEP( 9, bndBM, bndBE, 0)
        CTC_STEP(10, bndBM, bndBE, 0) CTC_STEP(11, bndBM, bndBE, 0)
        CTC_STEP(12, bndBM, bndBE, 0) CTC_STEP(13, bndBM, bndBE, 0)
        CTC_STEP(14, bndBM, bndBE, 0)
        STORE_BLK(127)
        asm volatile("" ::: "memory");
        if (lane == 0) *mflag = 128;
    }
#undef CTC_STEP
#undef RUN_BLOCK
#undef LOAD_BLK
#undef STORE_BLK

    // loss: states 399 (wave3 lane7: m1,E1) and 400 (wave3 lane8: m0,E0).
    // log2(value) = E + log2(m); lse2 in log2 domain; back to natural log.
    const float Am = __shfl(m1, 7, 64);
    const int   Ae = __shfl(E1, 7, 64);
    const float Bm = __shfl(m0, 8, 64);
    const int   Be = __shfl(E0, 8, 64);
    if (wid == 3 && lane == 0) {
        const float A = (float)Ae + __builtin_amdgcn_logf(Am);
        const float B = (float)Be + __builtin_amdgcn_logf(Bm);
        const float m = fmaxf(A, B);
        const float ls = m + __builtin_amdgcn_logf(
            __builtin_amdgcn_exp2f(A - m) + __builtin_amdgcn_exp2f(B - m));
        loss_ws[n] = -ls * K_LN2;
    }
}

__global__ void ctc_reduce(const float* __restrict__ ws, float* __restrict__ out)
{
    const int tid = threadIdx.x;   // 256 threads, 4 waves
    float v = ws[tid];
    v += __shfl_down(v, 32);
    v += __shfl_down(v, 16);
    v += __shfl_down(v, 8);
    v += __shfl_down(v, 4);
    v += __shfl_down(v, 2);
    v += __shfl_down(v, 1);
    __shared__ float p[4];
    if ((tid & 63) == 0) p[tid >> 6] = v;
    __syncthreads();
    if (tid == 0) out[0] = (p[0] + p[1]) + (p[2] + p[3]);
}

extern "C" void kernel_launch(void* const* d_in, const int* in_sizes, int n_in,
                              void* d_out, int out_size, void* d_ws, size_t ws_size,
                              hipStream_t stream)
{
    const float* pred   = (const float*)d_in[0];
    const int*   target = (const int*)d_in[1];
    // d_in[2] = input_length: unused by the reference computation
    const int*   tlen   = (const int*)d_in[3];
    float* ws = (float*)d_ws;

    ctc_alpha<<<NN, 256, 0, stream>>>(pred, target, tlen, ws);
    ctc_reduce<<<1, NN, 0, stream>>>(ws, (float*)d_out);
}